// Round 1
// baseline (63.550 us; speedup 1.0000x reference)
//
#include <hip/hip_runtime.h>

// Generalised shapelet transform, exact piecewise-linear integral.
// T=128 (times = arange), B=8, C=6, M=32, K=16, S=64 starts.
// Block = one (b,m); 256 threads = 64 starts x 4 integral quarters.
// Each thread merges integer grid points with shapelet knots over its
// quarter of [start, end], accumulating the exact quadratic integral.

__global__ __launch_bounds__(256) void shapelet_kernel(
    const float* __restrict__ path,       // (8,128,6)
    const float* __restrict__ lengths,    // (32,)
    const float* __restrict__ shapelets,  // (32,16,6)
    float* __restrict__ out)              // (8,32)
{
    const int bm  = (int)blockIdx.x;   // b*32 + m
    const int m   = bm & 31;
    const int b   = bm >> 5;
    const int tid = (int)threadIdx.x;

    __shared__ float pl[768];    // path row b: [t][c], t=0..127, c=0..5
    __shared__ float shp[96];    // shapelet m: [k][c]
    __shared__ float red[4];

    // Stage path row (192 float4) + shapelet (24 float4) into LDS.
    if (tid < 192) {
        ((float4*)pl)[tid] = ((const float4*)(path + b * 768))[tid];
    } else if (tid < 216) {
        ((float4*)shp)[tid - 192] = ((const float4*)(shapelets + m * 96))[tid - 192];
    }
    const float len = lengths[m];   // block-uniform -> scalar load
    __syncthreads();

    const int s = tid >> 2;   // start index 0..63
    const int q = tid & 3;    // integral quarter 0..3

    const float start = ((float)s * (1.0f / 63.0f)) * (127.0f - len);
    const float kstep = len * (1.0f / 15.0f);
    const float inv_h = 15.0f / len;

    const int k0 = 4 * q;
    const int k1 = (q == 3) ? 15 : (k0 + 4);

    float tprev = start + (float)k0 * kstep;  // q=0: exactly start

    float dprev[6], dcur[6];
    {   // d at tprev
        const float t = tprev;
        int idx = (int)t; if (idx > 126) idx = 126;
        const float w = t - (float)idx;
        const float rel = (t - start) * inv_h;
        int si = (int)rel; if (si > 14) si = 14;
        const float sw = rel - (float)si;
        const float* p  = pl  + idx * 6;
        const float* sp = shp + si  * 6;
        #pragma unroll
        for (int c = 0; c < 6; ++c) {
            const float pv = p[c]  + w  * (p[c + 6]  - p[c]);
            const float sv = sp[c] + sw * (sp[c + 6] - sp[c]);
            dprev[c] = pv - sv;
        }
    }

    float acc = 0.0f;
    int i = (int)tprev + 1;   // next integer grid point > tprev

    for (int k = k0 + 1; k <= k1; ++k) {
        const float tk = start + (float)k * kstep;  // same expr in all threads
        for (;;) {
            const float ti = (float)i;
            const bool is_int = (ti < tk);
            const float t = is_int ? ti : tk;

            int idx = (int)t; if (idx > 126) idx = 126;
            const float w = t - (float)idx;
            const float rel = (t - start) * inv_h;
            int si = (int)rel; if (si > 14) si = 14;
            const float sw = rel - (float)si;
            const float* p  = pl  + idx * 6;
            const float* sp = shp + si  * 6;

            float qsum = 0.0f;
            #pragma unroll
            for (int c = 0; c < 6; ++c) {
                const float pv = p[c]  + w  * (p[c + 6]  - p[c]);
                const float sv = sp[c] + sw * (sp[c + 6] - sp[c]);
                const float d  = pv - sv;
                qsum += dprev[c] * dprev[c] + dprev[c] * d + d * d;
                dcur[c] = d;
            }
            acc += (t - tprev) * (qsum * (1.0f / 3.0f));
            tprev = t;
            #pragma unroll
            for (int c = 0; c < 6; ++c) dprev[c] = dcur[c];

            if (is_int) { ++i; } else { break; }
        }
    }

    // Combine the 4 quarters (lanes differing in bits 0-1 share s).
    float v = acc;
    v += __shfl_xor(v, 1, 64);
    v += __shfl_xor(v, 2, 64);
    float disc = sqrtf(v);

    // Min over the 16 s-values resident in this wave (lane bits 2-5).
    disc = fminf(disc, __shfl_xor(disc, 4, 64));
    disc = fminf(disc, __shfl_xor(disc, 8, 64));
    disc = fminf(disc, __shfl_xor(disc, 16, 64));
    disc = fminf(disc, __shfl_xor(disc, 32, 64));

    if ((tid & 63) == 0) red[tid >> 6] = disc;
    __syncthreads();
    if (tid == 0) {
        out[bm] = fminf(fminf(red[0], red[1]), fminf(red[2], red[3]));
    }
}

extern "C" void kernel_launch(void* const* d_in, const int* in_sizes, int n_in,
                              void* d_out, int out_size, void* d_ws, size_t ws_size,
                              hipStream_t stream)
{
    // d_in order: times(128) [unused: arange], path(8*128*6),
    //             lengths(32), shapelets(32*16*6)
    const float* path      = (const float*)d_in[1];
    const float* lengths   = (const float*)d_in[2];
    const float* shapelets = (const float*)d_in[3];
    float* out = (float*)d_out;

    shapelet_kernel<<<dim3(256), dim3(256), 0, stream>>>(path, lengths, shapelets, out);
}

// Round 2
// 62.271 us; speedup vs baseline: 1.0206x; 1.0206x over previous
//
#include <hip/hip_runtime.h>

// Generalised shapelet transform, exact piecewise-linear integral.
// T=128 (times = arange), B=8, C=6, M=32, K=16, S=64 starts.
// Block = one (b,m); 1024 threads = 64 starts x 16 knot-segments
// (segment 15 idle: only 15 knot intervals). Each thread integrates
// exactly over one knot interval, merging interior integer grid points.
// 16 waves/block -> 4 waves/SIMD for latency hiding.

__global__ __launch_bounds__(1024) void shapelet_kernel(
    const float* __restrict__ path,       // (8,128,6)
    const float* __restrict__ lengths,    // (32,)
    const float* __restrict__ shapelets,  // (32,16,6)
    float* __restrict__ out)              // (8,32)
{
    const int bm  = (int)blockIdx.x;   // b*32 + m
    const int m   = bm & 31;
    const int b   = bm >> 5;
    const int tid = (int)threadIdx.x;

    __shared__ float pl[768];    // path row b: [t][c]
    __shared__ float shp[96];    // shapelet m: [k][c]
    __shared__ float red[16];

    if (tid < 192) {
        ((float4*)pl)[tid] = ((const float4*)(path + b * 768))[tid];
    } else if (tid < 216) {
        ((float4*)shp)[tid - 192] = ((const float4*)(shapelets + m * 96))[tid - 192];
    }
    const float len = lengths[m];   // block-uniform
    __syncthreads();

    const int s   = tid >> 4;   // start index 0..63
    const int seg = tid & 15;   // knot segment 0..15 (15 inactive)

    const float start = ((float)s * (1.0f / 63.0f)) * (127.0f - len);
    const float kstep = len * (1.0f / 15.0f);
    const float inv_h = 15.0f / len;

    float acc = 0.0f;

    if (seg < 15) {
        // Knot endpoints — same fp expression in every thread so adjacent
        // segments' boundaries agree bit-exactly.
        const float tL = start + (float)seg * kstep;
        const float tR = start + (float)(seg + 1) * kstep;

        // Shapelet endpoints for this segment (constant: si == seg).
        float s0[6], sd[6];
        {
            const float2* q2 = (const float2*)(shp + seg * 6);
            const float2 a0 = q2[0], a1 = q2[1], a2 = q2[2];
            const float2 b0 = q2[3], b1 = q2[4], b2 = q2[5];
            s0[0] = a0.x; s0[1] = a0.y; s0[2] = a1.x;
            s0[3] = a1.y; s0[4] = a2.x; s0[5] = a2.y;
            sd[0] = b0.x - s0[0]; sd[1] = b0.y - s0[1]; sd[2] = b1.x - s0[2];
            sd[3] = b1.y - s0[3]; sd[4] = b2.x - s0[4]; sd[5] = b2.y - s0[5];
        }

        float dprev[6];
        auto eval = [&](float t, float* d) {
            int idx = (int)t; if (idx > 126) idx = 126;
            const float w  = t - (float)idx;
            const float sw = (t - start) * inv_h - (float)seg;
            const float2* p2 = (const float2*)(pl + idx * 6);
            const float2 r0 = p2[0], r1 = p2[1], r2 = p2[2];
            const float2 r3 = p2[3], r4 = p2[4], r5 = p2[5];
            const float pa[6] = { r0.x, r0.y, r1.x, r1.y, r2.x, r2.y };
            const float pb[6] = { r3.x, r3.y, r4.x, r4.y, r5.x, r5.y };
            #pragma unroll
            for (int c = 0; c < 6; ++c) {
                const float pv = pa[c] + w * (pb[c] - pa[c]);
                const float sv = s0[c] + sw * sd[c];
                d[c] = pv - sv;
            }
        };

        eval(tL, dprev);
        float tprev = tL;

        int i = (int)tL + 1;   // first integer point > tL
        for (;;) {
            const float ti = (float)i;
            const bool is_int = (ti < tR);
            const float t = is_int ? ti : tR;

            float d[6];
            eval(t, d);
            float qsum = 0.0f;
            #pragma unroll
            for (int c = 0; c < 6; ++c) {
                qsum += dprev[c] * dprev[c] + dprev[c] * d[c] + d[c] * d[c];
                dprev[c] = d[c];
            }
            acc += (t - tprev) * (qsum * (1.0f / 3.0f));
            tprev = t;

            if (!is_int) break;
            ++i;
        }
    }

    // Sum the 16 segment partials (lane bits 0-3 share s).
    float v = acc;
    v += __shfl_xor(v, 1, 64);
    v += __shfl_xor(v, 2, 64);
    v += __shfl_xor(v, 4, 64);
    v += __shfl_xor(v, 8, 64);
    float disc = sqrtf(v);

    // Min over the 4 s-values in this wave (lane bits 4-5).
    disc = fminf(disc, __shfl_xor(disc, 16, 64));
    disc = fminf(disc, __shfl_xor(disc, 32, 64));

    if ((tid & 63) == 0) red[tid >> 6] = disc;
    __syncthreads();
    if (tid == 0) {
        float r = red[0];
        #pragma unroll
        for (int wv = 1; wv < 16; ++wv) r = fminf(r, red[wv]);
        out[bm] = r;
    }
}

extern "C" void kernel_launch(void* const* d_in, const int* in_sizes, int n_in,
                              void* d_out, int out_size, void* d_ws, size_t ws_size,
                              hipStream_t stream)
{
    // d_in order: times(128) [unused: arange], path(8*128*6),
    //             lengths(32), shapelets(32*16*6)
    const float* path      = (const float*)d_in[1];
    const float* lengths   = (const float*)d_in[2];
    const float* shapelets = (const float*)d_in[3];
    float* out = (float*)d_out;

    shapelet_kernel<<<dim3(256), dim3(1024), 0, stream>>>(path, lengths, shapelets, out);
}